// Round 8
// baseline (146.508 us; speedup 1.0000x reference)
//
#include <hip/hip_runtime.h>

// Ultimus: out = x + softmax((x@Kw+Kb)@(x@Qw+Qb)^T / sqrt(8)) @ (x@Vw+Vb) @ Zw + Zb
// N=8192, D_IN=48, D_ATTN=8, fp32 in/out.
//
// R8: row-per-lane attention, VECTOR-pipelined uniform loads.
// R7 post-mortem: forcing Q/V onto the scalar pipe (s_load) serialized the
// loop — SMEM completes out-of-order on CDNA, so every consume needs
// lgkmcnt(0), exposing full L2 latency per unroll group. Fix: opaque VGPR
// zero in the address so the compiler emits global_load_dwordx4 (in-order,
// fine-grained vmcnt, same-address lanes coalesce to one 64B broadcast).
// Also: memset dispatch removed (per-block maxima via plain stores, reduced
// in-kernel).
//
//  - Bound-softmax (Cauchy-Schwarz row bound) => fixed per-row exponent
//    shift; partials over disjoint j-chunks combine by pure addition.
//  - f16 storage + v_dot2_f32_f16; per-lane private accumulators; no
//    shfl/LDS/atomics in the hot loop.
//
// ws layout (floats):
//   [0, 32768)        Xksf16[8192]   8 f16/row (k * log2e/sqrt(8)), uint4/row
//   [32768, 98304)    QV             per j-pair p: 16 dwords =
//                                    q[2p](4) | q[2p+1](4) | vpair(8), where
//                                    vpair dword c = half2(V[2p][c],V[2p+1][c])
//   [98304, 98560)    bmax[256]      per-proj-block max ||q||^2 (plain store)
//   [98560, ...)      part[nch][8192][9]  fp32 partials: acc[0:8], l at [8]

#define QV_OFF   32768
#define BMAX_OFF 98304
#define PART_OFF 98560

typedef _Float16 f16x2 __attribute__((ext_vector_type(2)));

union HU { unsigned u; f16x2 h; };

static __device__ __forceinline__ unsigned pku(float a, float b) {
    auto v = __builtin_amdgcn_cvt_pkrtz(a, b);   // __fp16 vec2
    union { decltype(v) v2; unsigned u; } t;
    t.v2 = v;
    return t.u;
}
static __device__ __forceinline__ f16x2 asH2(unsigned u) {
    HU t; t.u = u; return t.h;
}
static __device__ __forceinline__ float fdot2(f16x2 a, f16x2 b, float c) {
#if __has_builtin(__builtin_amdgcn_fdot2)
    return __builtin_amdgcn_fdot2(a, b, c, false);
#else
    return fmaf((float)a.x, (float)b.x, fmaf((float)a.y, (float)b.y, c));
#endif
}

__global__ __launch_bounds__(256) void proj_kernel(
    const float* __restrict__ x,
    const float* __restrict__ Kw, const float* __restrict__ Kb,
    const float* __restrict__ Qw, const float* __restrict__ Qb,
    const float* __restrict__ Vw, const float* __restrict__ Vb,
    unsigned* __restrict__ Xksf16, unsigned* __restrict__ QV,
    float* __restrict__ bmax)
{
    __shared__ float xs[32 * 49];     // +1 pad
    __shared__ float wAll[3 * 388];   // stride 388 (mod 32 = 4) spreads 3 mats
    __shared__ float bs[24];
    __shared__ float outv[32][25];    // 24 cols + pad
    const int tid = threadIdx.x;
    const int r0 = blockIdx.x * 32;

    for (int i = tid; i < 1536; i += 256) {
        int r = i / 48, c = i - r * 48;
        xs[r * 49 + c] = x[r0 * 48 + i];
    }
    for (int i = tid; i < 384; i += 256) {
        wAll[i]       = Kw[i];
        wAll[388 + i] = Qw[i];
        wAll[776 + i] = Vw[i];
    }
    if (tid < 8)       bs[tid] = Kb[tid];
    else if (tid < 16) bs[tid] = Qb[tid - 8];
    else if (tid < 24) bs[tid] = Vb[tid - 16];
    __syncthreads();

    // thread = (row rl, col-group g): cols 3g..3g+2 of row r0+rl
    const int rl = tid >> 3;
    const int g  = tid & 7;
    const int c0 = 3 * g;
    const float* xr = &xs[rl * 49];
    const float* w0 = &wAll[((c0 + 0) >> 3) * 388 + ((c0 + 0) & 7)];
    const float* w1 = &wAll[((c0 + 1) >> 3) * 388 + ((c0 + 1) & 7)];
    const float* w2 = &wAll[((c0 + 2) >> 3) * 388 + ((c0 + 2) & 7)];
    float a0 = bs[c0], a1 = bs[c0 + 1], a2 = bs[c0 + 2];
    #pragma unroll
    for (int k = 0; k < 48; k++) {
        const float xv = xr[k];
        a0 = fmaf(xv, w0[k * 8], a0);
        a1 = fmaf(xv, w1[k * 8], a1);
        a2 = fmaf(xv, w2[k * 8], a2);
    }
    outv[rl][c0] = a0; outv[rl][c0 + 1] = a1; outv[rl][c0 + 2] = a2;
    __syncthreads();

    const float kscale = 0.51008732149f;  // (1/sqrt(8)) * log2(e)
    if (tid < 32) {                       // K rows, f16 packed, pre-scaled
        uint4 o;
        o.x = pku(outv[tid][0] * kscale, outv[tid][1] * kscale);
        o.y = pku(outv[tid][2] * kscale, outv[tid][3] * kscale);
        o.z = pku(outv[tid][4] * kscale, outv[tid][5] * kscale);
        o.w = pku(outv[tid][6] * kscale, outv[tid][7] * kscale);
        ((uint4*)Xksf16)[r0 + tid] = o;
    } else if (tid < 64) {                // Q rows -> QV slot (pair p, j&1)
        const int r = tid - 32;
        const int j = r0 + r;
        uint4 o;
        o.x = pku(outv[r][8],  outv[r][9]);
        o.y = pku(outv[r][10], outv[r][11]);
        o.z = pku(outv[r][12], outv[r][13]);
        o.w = pku(outv[r][14], outv[r][15]);
        ((uint4*)QV)[(j >> 1) * 4 + (j & 1)] = o;
    } else if (tid < 192) {               // V pair-interleaved -> QV dwords 8..15
        const int t2 = tid - 64;
        const int p = t2 >> 3, c = t2 & 7;
        const int pg = blockIdx.x * 16 + p;
        QV[pg * 16 + 8 + c] = pku(outv[2 * p][16 + c], outv[2 * p + 1][16 + c]);
    } else if (tid < 224) {               // block-max ||q||^2 (fp32), plain store
        const int r = tid - 192;
        float n2 = 0.f;
        #pragma unroll
        for (int c = 0; c < 8; c++) n2 = fmaf(outv[r][8 + c], outv[r][8 + c], n2);
        #pragma unroll
        for (int off = 16; off > 0; off >>= 1)
            n2 = fmaxf(n2, __shfl_xor(n2, off, 64));
        if (r == 0) bmax[blockIdx.x] = n2;
    }
}

// grid = 128 row-groups (64 rows; row = lane) x nch j-chunks.
// Wave w of a block handles pairs [(chunk*4 + w)*ppw, +ppw).
__global__ __launch_bounds__(256) void attn_kernel(
    const unsigned* __restrict__ Xksf16, const unsigned* __restrict__ QV,
    const float* __restrict__ bmax,
    float* __restrict__ part, int ppw)
{
    __shared__ float red[4][64][13];   // stride 13: conflict-free lane writes
    const int tid  = threadIdx.x;
    const int lane = tid & 63;
    const int wv   = tid >> 6;
    const int rgrp  = blockIdx.x & 127;
    const int chunk = blockIdx.x >> 7;
    const int row   = rgrp * 64 + lane;

    // qmax2 = max over the 256 per-proj-block maxima (coalesced + butterfly)
    float m = fmaxf(fmaxf(bmax[lane], bmax[64 + lane]),
                    fmaxf(bmax[128 + lane], bmax[192 + lane]));
    #pragma unroll
    for (int off = 32; off > 0; off >>= 1)
        m = fmaxf(m, __shfl_xor(m, off, 64));
    const float qmax2 = m;

    const uint4 kv = ((const uint4*)Xksf16)[row];   // coalesced 16B/lane
    f16x2 k2[4] = {asH2(kv.x), asH2(kv.y), asH2(kv.z), asH2(kv.w)};
    float kn2 = fdot2(k2[0], k2[0], 0.f);
    kn2 = fdot2(k2[1], k2[1], kn2);
    kn2 = fdot2(k2[2], k2[2], kn2);
    kn2 = fdot2(k2[3], k2[3], kn2);
    const float sinit = -sqrtf(kn2 * qmax2);  // s <= -sinit: p in (0,~1]

    float l = 0.f, acc[8];
    #pragma unroll
    for (int c = 0; c < 8; c++) acc[c] = 0.f;

    const f16x2 one2 = asH2(0x3C003C00u);     // (1.0h, 1.0h)

    // Opaque zero in a VGPR: keeps the (actually uniform) address in vector
    // registers so loads stay global_load_dwordx4 (in-order, vmcnt-pipelined)
    // instead of s_load (out-of-order -> lgkmcnt(0) serialization, the R7 wall).
    int vzero;
    asm volatile("v_mov_b32 %0, 0" : "=v"(vzero));
    const uint4* QV4 = (const uint4*)QV
                     + ((size_t)(chunk * 4 + wv) * ppw) * 4 + vzero;

    #pragma unroll 2
    for (int p = 0; p < ppw; p++) {
        const uint4 qa = QV4[p * 4 + 0];      // q[2p]
        const uint4 qb = QV4[p * 4 + 1];      // q[2p+1]
        const uint4 va = QV4[p * 4 + 2];      // vpair dwords 0..3
        const uint4 vb = QV4[p * 4 + 3];      // vpair dwords 4..7
        float s0 = fdot2(k2[0], asH2(qa.x), sinit);
        s0 = fdot2(k2[1], asH2(qa.y), s0);
        s0 = fdot2(k2[2], asH2(qa.z), s0);
        s0 = fdot2(k2[3], asH2(qa.w), s0);
        float s1 = fdot2(k2[0], asH2(qb.x), sinit);
        s1 = fdot2(k2[1], asH2(qb.y), s1);
        s1 = fdot2(k2[2], asH2(qb.z), s1);
        s1 = fdot2(k2[3], asH2(qb.w), s1);
        const f16x2 ph = asH2(pku(__builtin_amdgcn_exp2f(s0),
                                  __builtin_amdgcn_exp2f(s1)));
        l = fdot2(ph, one2, l);
        acc[0] = fdot2(ph, asH2(va.x), acc[0]);
        acc[1] = fdot2(ph, asH2(va.y), acc[1]);
        acc[2] = fdot2(ph, asH2(va.z), acc[2]);
        acc[3] = fdot2(ph, asH2(va.w), acc[3]);
        acc[4] = fdot2(ph, asH2(vb.x), acc[4]);
        acc[5] = fdot2(ph, asH2(vb.y), acc[5]);
        acc[6] = fdot2(ph, asH2(vb.z), acc[6]);
        acc[7] = fdot2(ph, asH2(vb.w), acc[7]);
    }

    // merge the block's 4 waves once via LDS (no atomics, no butterfly)
    #pragma unroll
    for (int c = 0; c < 8; c++) red[wv][lane][c] = acc[c];
    red[wv][lane][8] = l;
    __syncthreads();
    for (int e = tid; e < 576; e += 256) {
        const int r = e / 9, c = e - r * 9;
        const float s = red[0][r][c] + red[1][r][c] + red[2][r][c] + red[3][r][c];
        part[((size_t)chunk * 8192 + rgrp * 64 + r) * 9 + c] = s;
    }
}

__global__ __launch_bounds__(256) void finish_kernel(
    const float* __restrict__ x,
    const float* __restrict__ Zw, const float* __restrict__ Zb,
    const float* __restrict__ part, float* __restrict__ out, int nch)
{
    __shared__ float Zs[128 * 9];
    __shared__ float zw_s[384];
    __shared__ float zb_s[48];
    const int tid = threadIdx.x;
    const int r0 = blockIdx.x * 128;

    for (int i = tid; i < 384; i += 256) zw_s[i] = Zw[i];
    if (tid < 48) zb_s[tid] = Zb[tid];

    if (tid < 128) {
        const int row = r0 + tid;
        float a[9];
        #pragma unroll
        for (int c = 0; c < 9; c++) a[c] = 0.f;
        for (int ch = 0; ch < nch; ch++) {
            const float* p = part + ((size_t)ch * 8192 + row) * 9;
            #pragma unroll
            for (int c = 0; c < 9; c++) a[c] += p[c];
        }
        const float inv = 1.0f / a[8];
        #pragma unroll
        for (int c = 0; c < 8; c++) Zs[tid * 9 + c] = a[c] * inv;
    }
    __syncthreads();

    for (int e = tid; e < 128 * 48; e += 256) {
        const int r = e / 48, c = e - r * 48;
        float o = x[r0 * 48 + e] + zb_s[c];
        #pragma unroll
        for (int k = 0; k < 8; k++) o = fmaf(Zs[r * 9 + k], zw_s[k * 48 + c], o);
        out[r0 * 48 + e] = o;
    }
}

extern "C" void kernel_launch(void* const* d_in, const int* in_sizes, int n_in,
                              void* d_out, int out_size, void* d_ws, size_t ws_size,
                              hipStream_t stream) {
    const float* x  = (const float*)d_in[0];
    const float* Kw = (const float*)d_in[1];
    const float* Kb = (const float*)d_in[2];
    const float* Qw = (const float*)d_in[3];
    const float* Qb = (const float*)d_in[4];
    const float* Vw = (const float*)d_in[5];
    const float* Vb = (const float*)d_in[6];
    const float* Zw = (const float*)d_in[7];
    const float* Zb = (const float*)d_in[8];
    float* out = (float*)d_out;

    float* ws = (float*)d_ws;
    unsigned* Xksf16 = (unsigned*)ws;
    unsigned* QV     = (unsigned*)(ws + QV_OFF);
    float* bmax      = ws + BMAX_OFF;
    float* part      = ws + PART_OFF;

    // pick largest chunk count that fits the workspace (deterministic per session)
    int nch = 16;
    const size_t avail = ws_size / 4;
    while (nch > 1 && (size_t)PART_OFF + (size_t)nch * 8192 * 9 > avail) nch >>= 1;
    const int ppw = 1024 / nch;   // j-pairs per wave (4096 pairs / (nch*4 waves))

    proj_kernel<<<256, 256, 0, stream>>>(x, Kw, Kb, Qw, Qb, Vw, Vb,
                                         Xksf16, QV, bmax);
    attn_kernel<<<128 * nch, 256, 0, stream>>>(Xksf16, QV, bmax, part, ppw);
    finish_kernel<<<64, 256, 0, stream>>>(x, Zw, Zb, part, out, nch);
}

// Round 9
// 134.873 us; speedup vs baseline: 1.0863x; 1.0863x over previous
//
#include <hip/hip_runtime.h>

// Ultimus: out = x + softmax((x@Kw+Kb)@(x@Qw+Qb)^T / sqrt(8)) @ (x@Vw+Vb) @ Zw + Zb
// N=8192, D_IN=48, D_ATTN=8, fp32 in/out.
//
// R9: row-per-lane (4 rows/lane) + LDS-broadcast Q/V tile.
// R7: s_load uniform Q/V -> SMEM is out-of-order, lgkmcnt(0) serializes.
// R8: vector uniform Q/V -> same-address global_load still returns
//     16B x 64 lanes = 1KB through the ~64B/cyc L1 path (~16 cyc/load; 54 us).
// Only cheap broadcast path on CDNA4 = LDS same-address read (free).
// So: stage 32-pair QV tile to LDS (coalesced), hot loop does 4 uniform
// ds_read_b128/pair; each lane owns 4 rows' accumulators (amortize DS over
// 160 VALU-cyc); blocks cover disjoint rows => NO cross-lane/wave merge;
// partials stored column-major (coalesced), finish sums 128 chunks.
//
//  - Bound-softmax (Cauchy-Schwarz row bound) => fixed per-row exponent
//    shift; partials over disjoint j-chunks combine by pure addition.
//  - f16 storage + v_dot2_f32_f16; fp32 accumulators.
//
// ws layout (floats):
//   [0, 32768)        Xksf16[8192]   8 f16/row (k * log2e/sqrt(8)), uint4/row
//   [32768, 98304)    QV             per j-pair p: 16 dwords =
//                                    q[2p](4) | q[2p+1](4) | vpair(8), where
//                                    vpair dword c = half2(V[2p][c],V[2p+1][c])
//   [98304, 98560)    bmax[256]      per-proj-block max ||q||^2 (plain store)
//   [98560, ...)      part[nch][9][8192]  fp32 partials, c-major (coalesced)

#define QV_OFF   32768
#define BMAX_OFF 98304
#define PART_OFF 98560

typedef _Float16 f16x2 __attribute__((ext_vector_type(2)));

union HU { unsigned u; f16x2 h; };

static __device__ __forceinline__ unsigned pku(float a, float b) {
    auto v = __builtin_amdgcn_cvt_pkrtz(a, b);   // __fp16 vec2
    union { decltype(v) v2; unsigned u; } t;
    t.v2 = v;
    return t.u;
}
static __device__ __forceinline__ f16x2 asH2(unsigned u) {
    HU t; t.u = u; return t.h;
}
static __device__ __forceinline__ float fdot2(f16x2 a, f16x2 b, float c) {
#if __has_builtin(__builtin_amdgcn_fdot2)
    return __builtin_amdgcn_fdot2(a, b, c, false);
#else
    return fmaf((float)a.x, (float)b.x, fmaf((float)a.y, (float)b.y, c));
#endif
}

__global__ __launch_bounds__(256) void proj_kernel(
    const float* __restrict__ x,
    const float* __restrict__ Kw, const float* __restrict__ Kb,
    const float* __restrict__ Qw, const float* __restrict__ Qb,
    const float* __restrict__ Vw, const float* __restrict__ Vb,
    unsigned* __restrict__ Xksf16, unsigned* __restrict__ QV,
    float* __restrict__ bmax)
{
    __shared__ float xs[32 * 49];     // +1 pad
    __shared__ float wAll[3 * 388];   // stride 388 (mod 32 = 4) spreads 3 mats
    __shared__ float bs[24];
    __shared__ float outv[32][25];    // 24 cols + pad
    const int tid = threadIdx.x;
    const int r0 = blockIdx.x * 32;

    for (int i = tid; i < 1536; i += 256) {
        int r = i / 48, c = i - r * 48;
        xs[r * 49 + c] = x[r0 * 48 + i];
    }
    for (int i = tid; i < 384; i += 256) {
        wAll[i]       = Kw[i];
        wAll[388 + i] = Qw[i];
        wAll[776 + i] = Vw[i];
    }
    if (tid < 8)       bs[tid] = Kb[tid];
    else if (tid < 16) bs[tid] = Qb[tid - 8];
    else if (tid < 24) bs[tid] = Vb[tid - 16];
    __syncthreads();

    // thread = (row rl, col-group g): cols 3g..3g+2 of row r0+rl
    const int rl = tid >> 3;
    const int g  = tid & 7;
    const int c0 = 3 * g;
    const float* xr = &xs[rl * 49];
    const float* w0 = &wAll[((c0 + 0) >> 3) * 388 + ((c0 + 0) & 7)];
    const float* w1 = &wAll[((c0 + 1) >> 3) * 388 + ((c0 + 1) & 7)];
    const float* w2 = &wAll[((c0 + 2) >> 3) * 388 + ((c0 + 2) & 7)];
    float a0 = bs[c0], a1 = bs[c0 + 1], a2 = bs[c0 + 2];
    #pragma unroll
    for (int k = 0; k < 48; k++) {
        const float xv = xr[k];
        a0 = fmaf(xv, w0[k * 8], a0);
        a1 = fmaf(xv, w1[k * 8], a1);
        a2 = fmaf(xv, w2[k * 8], a2);
    }
    outv[rl][c0] = a0; outv[rl][c0 + 1] = a1; outv[rl][c0 + 2] = a2;
    __syncthreads();

    const float kscale = 0.51008732149f;  // (1/sqrt(8)) * log2(e)
    if (tid < 32) {                       // K rows, f16 packed, pre-scaled
        uint4 o;
        o.x = pku(outv[tid][0] * kscale, outv[tid][1] * kscale);
        o.y = pku(outv[tid][2] * kscale, outv[tid][3] * kscale);
        o.z = pku(outv[tid][4] * kscale, outv[tid][5] * kscale);
        o.w = pku(outv[tid][6] * kscale, outv[tid][7] * kscale);
        ((uint4*)Xksf16)[r0 + tid] = o;
    } else if (tid < 64) {                // Q rows -> QV slot (pair p, j&1)
        const int r = tid - 32;
        const int j = r0 + r;
        uint4 o;
        o.x = pku(outv[r][8],  outv[r][9]);
        o.y = pku(outv[r][10], outv[r][11]);
        o.z = pku(outv[r][12], outv[r][13]);
        o.w = pku(outv[r][14], outv[r][15]);
        ((uint4*)QV)[(j >> 1) * 4 + (j & 1)] = o;
    } else if (tid < 192) {               // V pair-interleaved -> QV dwords 8..15
        const int t2 = tid - 64;
        const int p = t2 >> 3, c = t2 & 7;
        const int pg = blockIdx.x * 16 + p;
        QV[pg * 16 + 8 + c] = pku(outv[2 * p][16 + c], outv[2 * p + 1][16 + c]);
    } else if (tid < 224) {               // block-max ||q||^2 (fp32), plain store
        const int r = tid - 192;
        float n2 = 0.f;
        #pragma unroll
        for (int c = 0; c < 8; c++) n2 = fmaf(outv[r][8 + c], outv[r][8 + c], n2);
        #pragma unroll
        for (int off = 16; off > 0; off >>= 1)
            n2 = fmaxf(n2, __shfl_xor(n2, off, 64));
        if (r == 0) bmax[blockIdx.x] = n2;
    }
}

// grid = 8 row-groups (1024 rows: 4 waves x 64 lanes x 4 rows/lane) x nch chunks.
// All 4 waves share one LDS QV tile; lanes own disjoint rows -> no merge.
__global__ __launch_bounds__(256) void attn_kernel(
    const unsigned* __restrict__ Xksf16, const unsigned* __restrict__ QV,
    const float* __restrict__ bmax,
    float* __restrict__ part, int P)
{
    __shared__ uint4 tile[256];    // up to 64 pairs (4 KB)
    const int tid  = threadIdx.x;
    const int lane = tid & 63;
    const int wv   = tid >> 6;
    const int g    = blockIdx.x & 7;
    const int ch   = blockIdx.x >> 3;

    // qmax2 = max over 256 per-proj-block maxima (coalesced + butterfly)
    float m = fmaxf(fmaxf(bmax[lane], bmax[64 + lane]),
                    fmaxf(bmax[128 + lane], bmax[192 + lane]));
    #pragma unroll
    for (int off = 32; off > 0; off >>= 1)
        m = fmaxf(m, __shfl_xor(m, off, 64));
    const float qmax2 = m;

    const int rbase = g * 1024 + wv * 256 + lane;   // rows: rbase + 64k, k=0..3
    f16x2 k2[4][4];
    float sinit[4], l[4], acc[4][8];
    #pragma unroll
    for (int k = 0; k < 4; k++) {
        const uint4 kv = ((const uint4*)Xksf16)[rbase + 64 * k];  // coalesced
        k2[k][0] = asH2(kv.x); k2[k][1] = asH2(kv.y);
        k2[k][2] = asH2(kv.z); k2[k][3] = asH2(kv.w);
        float kn2 = fdot2(k2[k][0], k2[k][0], 0.f);
        kn2 = fdot2(k2[k][1], k2[k][1], kn2);
        kn2 = fdot2(k2[k][2], k2[k][2], kn2);
        kn2 = fdot2(k2[k][3], k2[k][3], kn2);
        sinit[k] = -sqrtf(kn2 * qmax2);   // s <= -sinit: p in (0,~1]
        l[k] = 0.f;
        #pragma unroll
        for (int c = 0; c < 8; c++) acc[k][c] = 0.f;
    }

    const f16x2 one2 = asH2(0x3C003C00u);     // (1.0h, 1.0h)

    for (int t0 = 0; t0 < P; t0 += 64) {      // tile P<=64 pairs at a time
        const int np = min(64, P - t0);
        __syncthreads();
        for (int i = tid; i < np * 4; i += 256)
            tile[i] = ((const uint4*)QV)[((size_t)ch * P + t0) * 4 + i];
        __syncthreads();

        #pragma unroll 2
        for (int p = 0; p < np; p++) {
            // uniform-address ds_read_b128 x4: LDS broadcast, conflict-free
            const uint4 qa = tile[p * 4 + 0];
            const uint4 qb = tile[p * 4 + 1];
            const uint4 va = tile[p * 4 + 2];
            const uint4 vb = tile[p * 4 + 3];
            const f16x2 qa0 = asH2(qa.x), qa1 = asH2(qa.y),
                        qa2 = asH2(qa.z), qa3 = asH2(qa.w);
            const f16x2 qb0 = asH2(qb.x), qb1 = asH2(qb.y),
                        qb2 = asH2(qb.z), qb3 = asH2(qb.w);
            #pragma unroll
            for (int k = 0; k < 4; k++) {
                float s0 = fdot2(k2[k][0], qa0, sinit[k]);
                s0 = fdot2(k2[k][1], qa1, s0);
                s0 = fdot2(k2[k][2], qa2, s0);
                s0 = fdot2(k2[k][3], qa3, s0);
                float s1 = fdot2(k2[k][0], qb0, sinit[k]);
                s1 = fdot2(k2[k][1], qb1, s1);
                s1 = fdot2(k2[k][2], qb2, s1);
                s1 = fdot2(k2[k][3], qb3, s1);
                const f16x2 ph = asH2(pku(__builtin_amdgcn_exp2f(s0),
                                          __builtin_amdgcn_exp2f(s1)));
                l[k] = fdot2(ph, one2, l[k]);
                acc[k][0] = fdot2(ph, asH2(va.x), acc[k][0]);
                acc[k][1] = fdot2(ph, asH2(va.y), acc[k][1]);
                acc[k][2] = fdot2(ph, asH2(va.z), acc[k][2]);
                acc[k][3] = fdot2(ph, asH2(va.w), acc[k][3]);
                acc[k][4] = fdot2(ph, asH2(vb.x), acc[k][4]);
                acc[k][5] = fdot2(ph, asH2(vb.y), acc[k][5]);
                acc[k][6] = fdot2(ph, asH2(vb.z), acc[k][6]);
                acc[k][7] = fdot2(ph, asH2(vb.w), acc[k][7]);
            }
        }
    }

    // column-major partial store: coalesced across lanes, no merge needed
    #pragma unroll
    for (int k = 0; k < 4; k++) {
        const int row = rbase + 64 * k;
        #pragma unroll
        for (int c = 0; c < 8; c++)
            part[((size_t)(ch * 9 + c) << 13) + row] = acc[k][c];
        part[((size_t)(ch * 9 + 8) << 13) + row] = l[k];
    }
}

// grid = 128 blocks x 64 rows; thread (r = tid&63, slice = tid>>6 of nch/4 chunks)
__global__ __launch_bounds__(256) void finish_kernel(
    const float* __restrict__ x,
    const float* __restrict__ Zw, const float* __restrict__ Zb,
    const float* __restrict__ part, float* __restrict__ out, int nch)
{
    __shared__ float red[4][64][10];
    __shared__ float Zs[64][9];
    __shared__ float zw_s[384];
    __shared__ float zb_s[48];
    const int tid = threadIdx.x;
    const int r0 = blockIdx.x * 64;

    for (int i = tid; i < 384; i += 256) zw_s[i] = Zw[i];
    if (tid < 48) zb_s[tid] = Zb[tid];

    const int r = tid & 63, s = tid >> 6;
    const int row = r0 + r;
    const int cps = nch >> 2;
    float a[9];
    #pragma unroll
    for (int c = 0; c < 9; c++) a[c] = 0.f;
    for (int i = 0; i < cps; i++) {
        const int ch = s * cps + i;
        const float* p = part + ((size_t)(ch * 9) << 13) + row;
        #pragma unroll
        for (int c = 0; c < 9; c++) a[c] += p[(size_t)c << 13];  // coalesced
    }
    #pragma unroll
    for (int c = 0; c < 9; c++) red[s][r][c] = a[c];
    __syncthreads();
    if (tid < 64) {
        float b[9];
        #pragma unroll
        for (int c = 0; c < 9; c++)
            b[c] = red[0][tid][c] + red[1][tid][c] + red[2][tid][c] + red[3][tid][c];
        const float inv = 1.0f / b[8];
        #pragma unroll
        for (int c = 0; c < 8; c++) Zs[tid][c] = b[c] * inv;
    }
    __syncthreads();

    for (int e = tid; e < 64 * 48; e += 256) {
        const int rr = e / 48, c = e - rr * 48;
        float o = x[r0 * 48 + e] + zb_s[c];
        #pragma unroll
        for (int k = 0; k < 8; k++) o = fmaf(Zs[rr][k], zw_s[k * 48 + c], o);
        out[r0 * 48 + e] = o;
    }
}

extern "C" void kernel_launch(void* const* d_in, const int* in_sizes, int n_in,
                              void* d_out, int out_size, void* d_ws, size_t ws_size,
                              hipStream_t stream) {
    const float* x  = (const float*)d_in[0];
    const float* Kw = (const float*)d_in[1];
    const float* Kb = (const float*)d_in[2];
    const float* Qw = (const float*)d_in[3];
    const float* Qb = (const float*)d_in[4];
    const float* Vw = (const float*)d_in[5];
    const float* Vb = (const float*)d_in[6];
    const float* Zw = (const float*)d_in[7];
    const float* Zb = (const float*)d_in[8];
    float* out = (float*)d_out;

    float* ws = (float*)d_ws;
    unsigned* Xksf16 = (unsigned*)ws;
    unsigned* QV     = (unsigned*)(ws + QV_OFF);
    float* bmax      = ws + BMAX_OFF;
    float* part      = ws + PART_OFF;

    // largest chunk count whose partials fit the workspace
    int nch = 128;
    const size_t avail = ws_size / 4;
    while (nch > 4 && (size_t)PART_OFF + (size_t)nch * 9 * 8192 > avail) nch >>= 1;
    const int P = 4096 / nch;   // j-pairs per chunk

    proj_kernel<<<256, 256, 0, stream>>>(x, Kw, Kb, Qw, Qb, Vw, Vb,
                                         Xksf16, QV, bmax);
    attn_kernel<<<8 * nch, 256, 0, stream>>>(Xksf16, QV, bmax, part, P);
    finish_kernel<<<128, 256, 0, stream>>>(x, Zw, Zb, part, out, nch);
}

// Round 10
// 127.468 us; speedup vs baseline: 1.1494x; 1.0581x over previous
//
#include <hip/hip_runtime.h>
#include <hip/hip_fp16.h>

// Ultimus: out = x + softmax((x@Kw+Kb)@(x@Qw+Qb)^T / sqrt(8)) @ (x@Vw+Vb) @ Zw + Zb
// N=8192, D_IN=48, D_ATTN=8, fp32 in/out.
//
// R10: packed-f16 math via __half2 intrinsics (v_pk_fma_f16 guaranteed).
// R5..R9 post-mortem: __builtin_amdgcn_fdot2 was NOT available -> the
// fallback (cvt+fma chains) inflated VALU ~4x (R5: VALUBusy*dur = 26.9us vs
// 6us hand count). All f16 dot math now goes through __hfma2/__half2.
//   - Q and V both pair-interleaved in QV: dword c = (val[2p][c], val[2p+1][c])
//   - scores: f16x2 accumulate (init = packed sinit), extract->f32 exp2
//   - P*V and l: f16x2 accumulate; partials stored as f16 (halved traffic)
//   - LDS-broadcast tile (only cheap uniform-read path, R8/R7 lessons),
//     4 rows/lane, disjoint rows -> no merge, column-major partial stores.
//
// ws layout (floats):
//   [0, 32768)      Xksf16[8192] 8 f16/row (k * log2e/sqrt(8)), uint4/row
//   [32768, 98304)  QV per pair p: 16 dwords = q2pair[8] | v2pair[8]
//   [98304, 98560)  bmax[256] per-proj-block max ||q||^2 (plain store)
//   [98560, ...)    partH[nch][9][8192] f16 partials, c-major

#define QV_OFF   32768
#define BMAX_OFF 98304
#define PART_OFF 98560

union HU2 { unsigned u; __half2 h; };

static __device__ __forceinline__ unsigned pku(float a, float b) {
    auto v = __builtin_amdgcn_cvt_pkrtz(a, b);   // __fp16 vec2
    union { decltype(v) v2; unsigned u; } t;
    t.v2 = v;
    return t.u;
}
static __device__ __forceinline__ __half2 asH2(unsigned u) {
    HU2 t; t.u = u; return t.h;
}

__global__ __launch_bounds__(256) void proj_kernel(
    const float* __restrict__ x,
    const float* __restrict__ Kw, const float* __restrict__ Kb,
    const float* __restrict__ Qw, const float* __restrict__ Qb,
    const float* __restrict__ Vw, const float* __restrict__ Vb,
    unsigned* __restrict__ Xksf16, unsigned* __restrict__ QV,
    float* __restrict__ bmax)
{
    __shared__ float xs[32 * 49];     // +1 pad
    __shared__ float wAll[3 * 388];   // stride 388 (mod 32 = 4) spreads 3 mats
    __shared__ float bs[24];
    __shared__ float outv[32][25];    // 24 cols + pad
    const int tid = threadIdx.x;
    const int r0 = blockIdx.x * 32;

    for (int i = tid; i < 1536; i += 256) {
        int r = i / 48, c = i - r * 48;
        xs[r * 49 + c] = x[r0 * 48 + i];
    }
    for (int i = tid; i < 384; i += 256) {
        wAll[i]       = Kw[i];
        wAll[388 + i] = Qw[i];
        wAll[776 + i] = Vw[i];
    }
    if (tid < 8)       bs[tid] = Kb[tid];
    else if (tid < 16) bs[tid] = Qb[tid - 8];
    else if (tid < 24) bs[tid] = Vb[tid - 16];
    __syncthreads();

    // thread = (row rl, col-group g): cols 3g..3g+2 of row r0+rl
    const int rl = tid >> 3;
    const int g  = tid & 7;
    const int c0 = 3 * g;
    const float* xr = &xs[rl * 49];
    const float* w0 = &wAll[((c0 + 0) >> 3) * 388 + ((c0 + 0) & 7)];
    const float* w1 = &wAll[((c0 + 1) >> 3) * 388 + ((c0 + 1) & 7)];
    const float* w2 = &wAll[((c0 + 2) >> 3) * 388 + ((c0 + 2) & 7)];
    float a0 = bs[c0], a1 = bs[c0 + 1], a2 = bs[c0 + 2];
    #pragma unroll
    for (int k = 0; k < 48; k++) {
        const float xv = xr[k];
        a0 = fmaf(xv, w0[k * 8], a0);
        a1 = fmaf(xv, w1[k * 8], a1);
        a2 = fmaf(xv, w2[k * 8], a2);
    }
    outv[rl][c0] = a0; outv[rl][c0 + 1] = a1; outv[rl][c0 + 2] = a2;
    __syncthreads();

    // Phase 1: QV pair-interleaved, one dword per thread.
    // pair p (16/block), col c (8), m: 0=q(cols 8..15), 1=v(cols 16..23)
    {
        const int p = tid >> 4;
        const int c = (tid >> 1) & 7;
        const int m = tid & 1;
        const int col = (m ? 16 : 8) + c;
        QV[(blockIdx.x * 16 + p) * 16 + m * 8 + c] =
            pku(outv[2 * p][col], outv[2 * p + 1][col]);
    }
    const float kscale = 0.51008732149f;  // (1/sqrt(8)) * log2(e)
    if (tid < 32) {                       // K rows, f16 packed, pre-scaled
        uint4 o;
        o.x = pku(outv[tid][0] * kscale, outv[tid][1] * kscale);
        o.y = pku(outv[tid][2] * kscale, outv[tid][3] * kscale);
        o.z = pku(outv[tid][4] * kscale, outv[tid][5] * kscale);
        o.w = pku(outv[tid][6] * kscale, outv[tid][7] * kscale);
        ((uint4*)Xksf16)[r0 + tid] = o;
    }
    if (tid >= 192 && tid < 224) {        // block-max ||q||^2 (fp32)
        const int r = tid - 192;
        float n2 = 0.f;
        #pragma unroll
        for (int c = 0; c < 8; c++) n2 = fmaf(outv[r][8 + c], outv[r][8 + c], n2);
        #pragma unroll
        for (int off = 16; off > 0; off >>= 1)
            n2 = fmaxf(n2, __shfl_xor(n2, off, 64));
        if (r == 0) bmax[blockIdx.x] = n2;
    }
}

// grid = 8 row-groups (1024 rows: 4 waves x 64 lanes x 4 rows/lane) x nch chunks.
__global__ __launch_bounds__(256) void attn_kernel(
    const unsigned* __restrict__ Xksf16, const unsigned* __restrict__ QV,
    const float* __restrict__ bmax,
    __half* __restrict__ partH, int P)
{
    __shared__ uint4 tile[256];    // up to 64 pairs (4 KB)
    const int tid  = threadIdx.x;
    const int lane = tid & 63;
    const int wv   = tid >> 6;
    const int g    = blockIdx.x & 7;
    const int ch   = blockIdx.x >> 3;

    // qmax2 = max over 256 per-proj-block maxima
    float m = fmaxf(fmaxf(bmax[lane], bmax[64 + lane]),
                    fmaxf(bmax[128 + lane], bmax[192 + lane]));
    #pragma unroll
    for (int off = 32; off > 0; off >>= 1)
        m = fmaxf(m, __shfl_xor(m, off, 64));
    const float qmax2 = m;

    const int rbase = g * 1024 + wv * 256 + lane;   // rows: rbase + 64k
    __half2 k2b[4][8];                // k[r][c] duplicated in both halves
    __half2 sinit2[4], l2[4], acc2[4][8];
    const __half2 zero2 = __float2half2_rn(0.f);
    const __half2 one2  = __float2half2_rn(1.f);
    #pragma unroll
    for (int k = 0; k < 4; k++) {
        const uint4 kv = ((const uint4*)Xksf16)[rbase + 64 * k];  // coalesced
        const __half2 k01 = asH2(kv.x), k23 = asH2(kv.y),
                      k45 = asH2(kv.z), k67 = asH2(kv.w);
        k2b[k][0] = __low2half2(k01);  k2b[k][1] = __high2half2(k01);
        k2b[k][2] = __low2half2(k23);  k2b[k][3] = __high2half2(k23);
        k2b[k][4] = __low2half2(k45);  k2b[k][5] = __high2half2(k45);
        k2b[k][6] = __low2half2(k67);  k2b[k][7] = __high2half2(k67);
        float kn2 = 0.f;
        #pragma unroll
        for (int c = 0; c < 8; c++) {
            const float kf = __low2float(k2b[k][c]);
            kn2 = fmaf(kf, kf, kn2);
        }
        sinit2[k] = __float2half2_rn(-sqrtf(kn2 * qmax2));  // s <= 0: p in (0,1]
        l2[k] = zero2;
        #pragma unroll
        for (int c = 0; c < 8; c++) acc2[k][c] = zero2;
    }

    for (int t0 = 0; t0 < P; t0 += 64) {
        const int np = (P - t0 < 64) ? (P - t0) : 64;
        __syncthreads();
        for (int i = tid; i < np * 4; i += 256)
            tile[i] = ((const uint4*)QV)[((size_t)ch * P + t0) * 4 + i];
        __syncthreads();

        #pragma unroll 4
        for (int p = 0; p < np; p++) {
            // uniform-address ds_read_b128 x4: LDS broadcast, conflict-free
            const uint4 qp0 = tile[p * 4 + 0];   // q2pair c0..3
            const uint4 qp1 = tile[p * 4 + 1];   // q2pair c4..7
            const uint4 vp0 = tile[p * 4 + 2];   // v2pair c0..3
            const uint4 vp1 = tile[p * 4 + 3];   // v2pair c4..7
            const __half2 q0 = asH2(qp0.x), q1 = asH2(qp0.y),
                          q2 = asH2(qp0.z), q3 = asH2(qp0.w),
                          q4 = asH2(qp1.x), q5 = asH2(qp1.y),
                          q6 = asH2(qp1.z), q7 = asH2(qp1.w);
            const __half2 v0 = asH2(vp0.x), v1 = asH2(vp0.y),
                          v2 = asH2(vp0.z), v3 = asH2(vp0.w),
                          v4 = asH2(vp1.x), v5 = asH2(vp1.y),
                          v6 = asH2(vp1.z), v7 = asH2(vp1.w);
            #pragma unroll
            for (int k = 0; k < 4; k++) {
                __half2 s2 = sinit2[k];          // packed (sinit, sinit)
                s2 = __hfma2(k2b[k][0], q0, s2);
                s2 = __hfma2(k2b[k][1], q1, s2);
                s2 = __hfma2(k2b[k][2], q2, s2);
                s2 = __hfma2(k2b[k][3], q3, s2);
                s2 = __hfma2(k2b[k][4], q4, s2);
                s2 = __hfma2(k2b[k][5], q5, s2);
                s2 = __hfma2(k2b[k][6], q6, s2);
                s2 = __hfma2(k2b[k][7], q7, s2);
                const float p0 = __builtin_amdgcn_exp2f(__low2float(s2));
                const float p1 = __builtin_amdgcn_exp2f(__high2float(s2));
                const __half2 ph = asH2(pku(p0, p1));
                l2[k] = __hfma2(ph, one2, l2[k]);
                acc2[k][0] = __hfma2(ph, v0, acc2[k][0]);
                acc2[k][1] = __hfma2(ph, v1, acc2[k][1]);
                acc2[k][2] = __hfma2(ph, v2, acc2[k][2]);
                acc2[k][3] = __hfma2(ph, v3, acc2[k][3]);
                acc2[k][4] = __hfma2(ph, v4, acc2[k][4]);
                acc2[k][5] = __hfma2(ph, v5, acc2[k][5]);
                acc2[k][6] = __hfma2(ph, v6, acc2[k][6]);
                acc2[k][7] = __hfma2(ph, v7, acc2[k][7]);
            }
        }
    }

    // column-major f16 partial store: coalesced, no merge needed
    #pragma unroll
    for (int k = 0; k < 4; k++) {
        const int row = rbase + 64 * k;
        #pragma unroll
        for (int c = 0; c < 8; c++) {
            const float af = __low2float(acc2[k][c]) + __high2float(acc2[k][c]);
            partH[((size_t)(ch * 9 + c) << 13) + row] = __float2half_rn(af);
        }
        const float lf = __low2float(l2[k]) + __high2float(l2[k]);
        partH[((size_t)(ch * 9 + 8) << 13) + row] = __float2half_rn(lf);
    }
}

// grid = 128 blocks x 64 rows; thread (r = tid&63, slice = tid>>6)
__global__ __launch_bounds__(256) void finish_kernel(
    const float* __restrict__ x,
    const float* __restrict__ Zw, const float* __restrict__ Zb,
    const __half* __restrict__ partH, float* __restrict__ out, int nch)
{
    __shared__ float red[4][64][10];
    __shared__ float Zs[64][9];
    __shared__ float zw_s[384];
    __shared__ float zb_s[48];
    const int tid = threadIdx.x;
    const int r0 = blockIdx.x * 64;

    for (int i = tid; i < 384; i += 256) zw_s[i] = Zw[i];
    if (tid < 48) zb_s[tid] = Zb[tid];

    const int r = tid & 63, s = tid >> 6;
    const int row = r0 + r;
    const int cps = nch >> 2;
    float a[9];
    #pragma unroll
    for (int c = 0; c < 9; c++) a[c] = 0.f;
    for (int i = 0; i < cps; i++) {
        const int ch = s * cps + i;
        const __half* p = partH + ((size_t)(ch * 9) << 13) + row;
        #pragma unroll
        for (int c = 0; c < 9; c++) a[c] += __half2float(p[(size_t)c << 13]);
    }
    #pragma unroll
    for (int c = 0; c < 9; c++) red[s][r][c] = a[c];
    __syncthreads();
    if (tid < 64) {
        float b[9];
        #pragma unroll
        for (int c = 0; c < 9; c++)
            b[c] = red[0][tid][c] + red[1][tid][c] + red[2][tid][c] + red[3][tid][c];
        const float inv = 1.0f / b[8];
        #pragma unroll
        for (int c = 0; c < 8; c++) Zs[tid][c] = b[c] * inv;
    }
    __syncthreads();

    for (int e = tid; e < 64 * 48; e += 256) {
        const int rr = e / 48, c = e - rr * 48;
        float o = x[r0 * 48 + e] + zb_s[c];
        #pragma unroll
        for (int k = 0; k < 8; k++) o = fmaf(Zs[rr][k], zw_s[k * 48 + c], o);
        out[r0 * 48 + e] = o;
    }
}

extern "C" void kernel_launch(void* const* d_in, const int* in_sizes, int n_in,
                              void* d_out, int out_size, void* d_ws, size_t ws_size,
                              hipStream_t stream) {
    const float* x  = (const float*)d_in[0];
    const float* Kw = (const float*)d_in[1];
    const float* Kb = (const float*)d_in[2];
    const float* Qw = (const float*)d_in[3];
    const float* Qb = (const float*)d_in[4];
    const float* Vw = (const float*)d_in[5];
    const float* Vb = (const float*)d_in[6];
    const float* Zw = (const float*)d_in[7];
    const float* Zb = (const float*)d_in[8];
    float* out = (float*)d_out;

    float* ws = (float*)d_ws;
    unsigned* Xksf16 = (unsigned*)ws;
    unsigned* QV     = (unsigned*)(ws + QV_OFF);
    float* bmax      = ws + BMAX_OFF;
    __half* partH    = (__half*)(ws + PART_OFF);

    // largest chunk count whose f16 partials fit the workspace
    int nch = 128;
    while (nch > 4 &&
           (size_t)PART_OFF * 4 + (size_t)nch * 9 * 8192 * 2 > ws_size) nch >>= 1;
    const int P = 4096 / nch;   // j-pairs per chunk

    proj_kernel<<<256, 256, 0, stream>>>(x, Kw, Kb, Qw, Qb, Vw, Vb,
                                         Xksf16, QV, bmax);
    attn_kernel<<<8 * nch, 256, 0, stream>>>(Xksf16, QV, bmax, partH, P);
    finish_kernel<<<128, 256, 0, stream>>>(x, Zw, Zb, partH, out, nch);
}

// Round 11
// 115.545 us; speedup vs baseline: 1.2680x; 1.1032x over previous
//
#include <hip/hip_runtime.h>
#include <hip/hip_fp16.h>

// Ultimus: out = x + softmax((x@Kw+Kb)@(x@Qw+Qb)^T / sqrt(8)) @ (x@Vw+Vb) @ Zw + Zb
// N=8192, D_IN=48, D_ATTN=8, fp32 in/out.
//
// R11 = R7 skeleton (empirically fastest structure: row=lane, 64 rows/block,
// wave = j-slice, s_load uniform Q/V, ONE LDS merge) + guaranteed packed-f16
// math (v_pk_fma_f16 via __builtin_elementwise_fma on _Float16 vec2; R5-R10
// evidence says fdot2/__hfma2 paths were scalarizing, inflating VALU ~4x).
//
//  - Bound-softmax (Cauchy-Schwarz row bound) => fixed per-row exponent
//    shift; partials over disjoint j-chunks combine by pure addition.
//  - QV pair-interleaved: dword c of pair p = half2(val[2p][c], val[2p+1][c])
//    so one pk_fma accumulates scores for both j's of the pair at once.
//
// ws layout (floats):
//   [0, 32768)      Xksf16[8192] 8 f16/row (k * log2e/sqrt(8)), uint4/row
//   [32768, 98304)  QV per pair p: 16 dwords = q2pair[8] | v2pair[8]
//   [98304, 98560)  bmax[256] per-proj-block max ||q||^2 (plain store)
//   [98560, ...)    part[nch][8192][9] f32 partials: acc[0:8], l at [8]

#define QV_OFF   32768
#define BMAX_OFF 98304
#define PART_OFF 98560

typedef _Float16 hv2 __attribute__((ext_vector_type(2)));
union HVU { unsigned u; hv2 v; };

static __device__ __forceinline__ unsigned pku(float a, float b) {
    auto t = __builtin_amdgcn_cvt_pkrtz(a, b);
    union { decltype(t) x; unsigned u; } c; c.x = t; return c.u;
}
static __device__ __forceinline__ hv2 asV(unsigned u) { HVU t; t.u = u; return t.v; }
static __device__ __forceinline__ hv2 h2fma(hv2 a, hv2 b, hv2 c) {
#if __has_builtin(__builtin_elementwise_fma)
    return __builtin_elementwise_fma(a, b, c);
#else
    union { hv2 v; __half2 h; } A, B, C, D;
    A.v = a; B.v = b; C.v = c;
    D.h = __hfma2(A.h, B.h, C.h);
    return D.v;
#endif
}
static __device__ __forceinline__ unsigned dupL(unsigned u) {
    const unsigned lo = u & 0xFFFFu; return lo | (lo << 16);
}
static __device__ __forceinline__ unsigned dupH(unsigned u) {
    const unsigned hi = u >> 16; return hi | (hi << 16);
}

__global__ __launch_bounds__(256) void proj_kernel(
    const float* __restrict__ x,
    const float* __restrict__ Kw, const float* __restrict__ Kb,
    const float* __restrict__ Qw, const float* __restrict__ Qb,
    const float* __restrict__ Vw, const float* __restrict__ Vb,
    unsigned* __restrict__ Xksf16, unsigned* __restrict__ QV,
    float* __restrict__ bmax)
{
    __shared__ float xs[32 * 49];     // +1 pad
    __shared__ float wAll[3 * 388];   // stride 388 (mod 32 = 4) spreads 3 mats
    __shared__ float bs[24];
    __shared__ float outv[32][25];    // 24 cols + pad
    const int tid = threadIdx.x;
    const int r0 = blockIdx.x * 32;

    for (int i = tid; i < 1536; i += 256) {
        int r = i / 48, c = i - r * 48;
        xs[r * 49 + c] = x[r0 * 48 + i];
    }
    for (int i = tid; i < 384; i += 256) {
        wAll[i]       = Kw[i];
        wAll[388 + i] = Qw[i];
        wAll[776 + i] = Vw[i];
    }
    if (tid < 8)       bs[tid] = Kb[tid];
    else if (tid < 16) bs[tid] = Qb[tid - 8];
    else if (tid < 24) bs[tid] = Vb[tid - 16];
    __syncthreads();

    const int rl = tid >> 3;
    const int g  = tid & 7;
    const int c0 = 3 * g;
    const float* xr = &xs[rl * 49];
    const float* w0 = &wAll[((c0 + 0) >> 3) * 388 + ((c0 + 0) & 7)];
    const float* w1 = &wAll[((c0 + 1) >> 3) * 388 + ((c0 + 1) & 7)];
    const float* w2 = &wAll[((c0 + 2) >> 3) * 388 + ((c0 + 2) & 7)];
    float a0 = bs[c0], a1 = bs[c0 + 1], a2 = bs[c0 + 2];
    #pragma unroll
    for (int k = 0; k < 48; k++) {
        const float xv = xr[k];
        a0 = fmaf(xv, w0[k * 8], a0);
        a1 = fmaf(xv, w1[k * 8], a1);
        a2 = fmaf(xv, w2[k * 8], a2);
    }
    outv[rl][c0] = a0; outv[rl][c0 + 1] = a1; outv[rl][c0 + 2] = a2;
    __syncthreads();

    // QV pair-interleaved: pair p (16/block), col c (8), m: 0=q, 1=v
    {
        const int p = tid >> 4;
        const int c = (tid >> 1) & 7;
        const int m = tid & 1;
        const int col = (m ? 16 : 8) + c;
        QV[(blockIdx.x * 16 + p) * 16 + m * 8 + c] =
            pku(outv[2 * p][col], outv[2 * p + 1][col]);
    }
    const float kscale = 0.51008732149f;  // (1/sqrt(8)) * log2(e)
    if (tid < 32) {                       // K rows, f16 packed, pre-scaled
        uint4 o;
        o.x = pku(outv[tid][0] * kscale, outv[tid][1] * kscale);
        o.y = pku(outv[tid][2] * kscale, outv[tid][3] * kscale);
        o.z = pku(outv[tid][4] * kscale, outv[tid][5] * kscale);
        o.w = pku(outv[tid][6] * kscale, outv[tid][7] * kscale);
        ((uint4*)Xksf16)[r0 + tid] = o;
    }
    if (tid >= 192 && tid < 224) {        // block-max ||q||^2 (fp32)
        const int r = tid - 192;
        float n2 = 0.f;
        #pragma unroll
        for (int c = 0; c < 8; c++) n2 = fmaf(outv[r][8 + c], outv[r][8 + c], n2);
        #pragma unroll
        for (int off = 16; off > 0; off >>= 1)
            n2 = fmaxf(n2, __shfl_xor(n2, off, 64));
        if (r == 0) bmax[blockIdx.x] = n2;
    }
}

// grid = 128 row-groups (64 rows; row = lane) x nch j-chunks.
// Wave w handles pairs [(chunk*4 + w)*ppw, +ppw) via uniform s_load.
__global__ __launch_bounds__(256) void attn_kernel(
    const unsigned* __restrict__ Xksf16, const unsigned* __restrict__ QV,
    const float* __restrict__ bmax,
    float* __restrict__ part, int ppw)
{
    __shared__ float red[4][64][13];   // stride 13: conflict-light
    const int tid  = threadIdx.x;
    const int lane = tid & 63;
    const int wv   = tid >> 6;
    const int rgrp  = blockIdx.x & 127;
    const int chunk = blockIdx.x >> 7;
    const int row   = rgrp * 64 + lane;

    // qmax2 = max over 256 per-proj-block maxima
    float m = fmaxf(fmaxf(bmax[lane], bmax[64 + lane]),
                    fmaxf(bmax[128 + lane], bmax[192 + lane]));
    #pragma unroll
    for (int off = 32; off > 0; off >>= 1)
        m = fmaxf(m, __shfl_xor(m, off, 64));
    const float qmax2 = m;

    const uint4 kv = ((const uint4*)Xksf16)[row];   // coalesced 16B/lane
    unsigned kd[8];
    kd[0] = dupL(kv.x); kd[1] = dupH(kv.x);
    kd[2] = dupL(kv.y); kd[3] = dupH(kv.y);
    kd[4] = dupL(kv.z); kd[5] = dupH(kv.z);
    kd[6] = dupL(kv.w); kd[7] = dupH(kv.w);
    float kn2 = 0.f;
    #pragma unroll
    for (int c = 0; c < 8; c++) {
        const float kf = (float)asV(kd[c]).x;
        kn2 = fmaf(kf, kf, kn2);
    }
    const float sinit = -sqrtf(kn2 * qmax2);  // s <= -sinit: p in (0,~1]
    const hv2 sinit2 = asV(pku(sinit, sinit));
    const hv2 one2   = asV(0x3C003C00u);
    hv2 l2 = asV(0u), acc[8];
    #pragma unroll
    for (int c = 0; c < 8; c++) acc[c] = asV(0u);

    // provably wave-uniform pair base -> s_load_dwordx16 (scalar pipe);
    // latency hidden by 8 waves/SIMD (R7 evidence: structure ran fine).
    const int pbase = __builtin_amdgcn_readfirstlane((chunk * 4 + wv) * ppw);
    const uint4* QV4 = (const uint4*)QV + (size_t)pbase * 4;

    #pragma unroll 4
    for (int p = 0; p < ppw; p++) {
        const uint4 qp0 = QV4[p * 4 + 0];   // q2pair c0..3
        const uint4 qp1 = QV4[p * 4 + 1];   // q2pair c4..7
        const uint4 vp0 = QV4[p * 4 + 2];   // v2pair c0..3
        const uint4 vp1 = QV4[p * 4 + 3];   // v2pair c4..7
        hv2 s2 = sinit2;
        s2 = h2fma(asV(kd[0]), asV(qp0.x), s2);
        s2 = h2fma(asV(kd[1]), asV(qp0.y), s2);
        s2 = h2fma(asV(kd[2]), asV(qp0.z), s2);
        s2 = h2fma(asV(kd[3]), asV(qp0.w), s2);
        s2 = h2fma(asV(kd[4]), asV(qp1.x), s2);
        s2 = h2fma(asV(kd[5]), asV(qp1.y), s2);
        s2 = h2fma(asV(kd[6]), asV(qp1.z), s2);
        s2 = h2fma(asV(kd[7]), asV(qp1.w), s2);
        const float pa = __builtin_amdgcn_exp2f((float)s2.x);
        const float pb = __builtin_amdgcn_exp2f((float)s2.y);
        const hv2 ph = asV(pku(pa, pb));
        l2 = h2fma(ph, one2, l2);
        acc[0] = h2fma(ph, asV(vp0.x), acc[0]);
        acc[1] = h2fma(ph, asV(vp0.y), acc[1]);
        acc[2] = h2fma(ph, asV(vp0.z), acc[2]);
        acc[3] = h2fma(ph, asV(vp0.w), acc[3]);
        acc[4] = h2fma(ph, asV(vp1.x), acc[4]);
        acc[5] = h2fma(ph, asV(vp1.y), acc[5]);
        acc[6] = h2fma(ph, asV(vp1.z), acc[6]);
        acc[7] = h2fma(ph, asV(vp1.w), acc[7]);
    }

    // merge the block's 4 waves once via LDS (no atomics, no butterfly)
    #pragma unroll
    for (int c = 0; c < 8; c++)
        red[wv][lane][c] = (float)acc[c].x + (float)acc[c].y;
    red[wv][lane][8] = (float)l2.x + (float)l2.y;
    __syncthreads();
    for (int e = tid; e < 576; e += 256) {
        const int r = e / 9, c = e - r * 9;
        const float s = red[0][r][c] + red[1][r][c] + red[2][r][c] + red[3][r][c];
        part[((size_t)chunk * 8192 + rgrp * 64 + r) * 9 + c] = s;
    }
}

__global__ __launch_bounds__(256) void finish_kernel(
    const float* __restrict__ x,
    const float* __restrict__ Zw, const float* __restrict__ Zb,
    const float* __restrict__ part, float* __restrict__ out, int nch)
{
    __shared__ float Zs[128 * 9];
    __shared__ float zw_s[384];
    __shared__ float zb_s[48];
    const int tid = threadIdx.x;
    const int r0 = blockIdx.x * 128;

    for (int i = tid; i < 384; i += 256) zw_s[i] = Zw[i];
    if (tid < 48) zb_s[tid] = Zb[tid];

    if (tid < 128) {
        const int row = r0 + tid;
        float a[9];
        #pragma unroll
        for (int c = 0; c < 9; c++) a[c] = 0.f;
        for (int ch = 0; ch < nch; ch++) {
            const float* p = part + ((size_t)ch * 8192 + row) * 9;
            #pragma unroll
            for (int c = 0; c < 9; c++) a[c] += p[c];
        }
        const float inv = 1.0f / a[8];
        #pragma unroll
        for (int c = 0; c < 8; c++) Zs[tid * 9 + c] = a[c] * inv;
    }
    __syncthreads();

    for (int e = tid; e < 128 * 48; e += 256) {
        const int r = e / 48, c = e - r * 48;
        float o = x[r0 * 48 + e] + zb_s[c];
        #pragma unroll
        for (int k = 0; k < 8; k++) o = fmaf(Zs[r * 9 + k], zw_s[k * 48 + c], o);
        out[r0 * 48 + e] = o;
    }
}

extern "C" void kernel_launch(void* const* d_in, const int* in_sizes, int n_in,
                              void* d_out, int out_size, void* d_ws, size_t ws_size,
                              hipStream_t stream) {
    const float* x  = (const float*)d_in[0];
    const float* Kw = (const float*)d_in[1];
    const float* Kb = (const float*)d_in[2];
    const float* Qw = (const float*)d_in[3];
    const float* Qb = (const float*)d_in[4];
    const float* Vw = (const float*)d_in[5];
    const float* Vb = (const float*)d_in[6];
    const float* Zw = (const float*)d_in[7];
    const float* Zb = (const float*)d_in[8];
    float* out = (float*)d_out;

    float* ws = (float*)d_ws;
    unsigned* Xksf16 = (unsigned*)ws;
    unsigned* QV     = (unsigned*)(ws + QV_OFF);
    float* bmax      = ws + BMAX_OFF;
    float* part      = ws + PART_OFF;

    int nch = 16;
    const size_t avail = ws_size / 4;
    while (nch > 1 && (size_t)PART_OFF + (size_t)nch * 8192 * 9 > avail) nch >>= 1;
    const int ppw = 1024 / nch;   // j-pairs per wave (4096 pairs / (nch*4 waves))

    proj_kernel<<<256, 256, 0, stream>>>(x, Kw, Kb, Qw, Qb, Vw, Vb,
                                         Xksf16, QV, bmax);
    attn_kernel<<<128 * nch, 256, 0, stream>>>(Xksf16, QV, bmax, part, ppw);
    finish_kernel<<<64, 256, 0, stream>>>(x, Zw, Zb, part, out, nch);
}